// Round 9
// baseline (213.188 us; speedup 1.0000x reference)
//
#include <hip/hip_runtime.h>
#include <hip/hip_bf16.h>
#include <math.h>

#define BATCH 16
#define SEQ   2048
#define HID   128
#define DIM   64

#define KCOLS 16                       // k-columns per attention block
#define NKBLK (SEQ / KCOLS)            // 128 k-blocks per batch
#define CPLANE 1088                    // uint2 slots per qi-plane (1024 + skew room)
#define CACHE_BYTES (8 * CPLANE * 8)   // 69632 B dynamic LDS

typedef __attribute__((ext_vector_type(8))) short bf16x8;
typedef __attribute__((ext_vector_type(4))) float f32x4;

// 0.125 (1/sqrt(D)) * log2(e): folded into Wq so MFMA emits log2-domain scores
#define QSCALE 0.18033688011112042f
#define C0_PE  0.07195578314043169f   // ln(10000)/128

static __device__ __forceinline__ ushort f2bf(float f) {
    __hip_bfloat16 h = __float2bfloat16(f);
    return *reinterpret_cast<ushort*>(&h);
}

static __device__ __forceinline__ float fast_exp2(float x) {
#if __has_builtin(__builtin_amdgcn_exp2f)
    return __builtin_amdgcn_exp2f(x);
#else
    return exp2f(x);
#endif
}

static __device__ __forceinline__ unsigned packf16(float a, float b) {
    _Float16 ha = (_Float16)a, hb = (_Float16)b;
    unsigned short ua = __builtin_bit_cast(unsigned short, ha);
    unsigned short ub = __builtin_bit_cast(unsigned short, hb);
    return ((unsigned)ub << 16) | ua;
}

static __device__ __forceinline__ float2 unpackf16(unsigned u) {
    _Float16 lo = __builtin_bit_cast(_Float16, (unsigned short)(u & 0xffffu));
    _Float16 hi = __builtin_bit_cast(_Float16, (unsigned short)(u >> 16));
    return make_float2((float)lo, (float)hi);
}

// ---------------------------------------------------------------------------
// Prep (1024 blocks): wvf[h] = Wv[h,:]·Wf ;  Wt = bf16 [Wq*QSCALE | Wk]^T ;
// pe[s][h] = sinusoidal PE table (f32, 1 MB).
// ---------------------------------------------------------------------------
__global__ __launch_bounds__(256) void k_prep(
    const float* __restrict__ Wq, const float* __restrict__ Wk,
    const float* __restrict__ Wv, const float* __restrict__ Wf,
    ushort* __restrict__ Wt, float* __restrict__ wvf, float* __restrict__ pe) {
    const int gid = blockIdx.x * 256 + threadIdx.x;
    if (gid < HID) {
        float s = 0.f;
        #pragma unroll 8
        for (int d = 0; d < DIM; ++d) s += Wv[gid * DIM + d] * Wf[d];
        wvf[gid] = s;
    }
    if (gid < 128 * 128) {
        int col = gid >> 7, k = gid & 127;
        float v = (col < 64) ? Wq[k * DIM + col] * QSCALE : Wk[k * DIM + (col - 64)];
        Wt[gid] = f2bf(v);
    }
    {
        int s = gid >> 7, h = gid & 127;
        int he = h & ~1;
        float ang = (float)s * __expf(-(float)he * C0_PE);
        pe[gid] = (h & 1) ? __cosf(ang) : __sinf(ang);
    }
}

// ---------------------------------------------------------------------------
// QKV (MFMA): block = 64 rows, wave = 16 rows. NEW: Q/K tiles staged in LDS
// and written back as coalesced 16B stores (the old path did 32 scattered
// 2-byte stores per lane — write-combining disaster). Layout unchanged.
// ---------------------------------------------------------------------------
__global__ __launch_bounds__(256) void k_qkv(
    const float* __restrict__ x, const ushort* __restrict__ Wt,
    const float* __restrict__ wvf, const float* __restrict__ pe,
    ushort* __restrict__ Qb, ushort* __restrict__ Kb, float* __restrict__ vf)
{
    const int tid  = threadIdx.x;
    const int wave = tid >> 6;
    const int lane = tid & 63;
    const int quad = lane >> 4;
    const int col  = lane & 15;
    const int rowbase = blockIdx.x * 64 + wave * 16;
    const int grow = rowbase + col;
    const int srow = grow & (SEQ - 1);

    __shared__ ushort qs[64][72];      // 72-pad: 144B row stride, 16B-aligned
    __shared__ ushort ks[64][72];

    bf16x8 af[4];
    float vpart = 0.f;
    #pragma unroll
    for (int c = 0; c < 4; ++c) {
        const float* xp = x + (size_t)grow * HID + quad * 8 + c * 32;
        float4 v0 = *(const float4*)(xp);
        float4 v1 = *(const float4*)(xp + 4);
        const float* per = pe + (size_t)srow * HID + quad * 8 + c * 32;
        float4 p0 = *(const float4*)(per);
        float4 p1 = *(const float4*)(per + 4);
        float t[8] = {v0.x + p0.x, v0.y + p0.y, v0.z + p0.z, v0.w + p0.w,
                      v1.x + p1.x, v1.y + p1.y, v1.z + p1.z, v1.w + p1.w};
        const float* wp = wvf + quad * 8 + c * 32;
        float4 w0 = *(const float4*)(wp);
        float4 w1 = *(const float4*)(wp + 4);
        vpart += t[0] * w0.x + t[1] * w0.y + t[2] * w0.z + t[3] * w0.w +
                 t[4] * w1.x + t[5] * w1.y + t[6] * w1.z + t[7] * w1.w;
        short* ap = (short*)&af[c];
        #pragma unroll
        for (int j = 0; j < 8; ++j) ap[j] = (short)f2bf(t[j]);
    }

    vpart += __shfl_xor(vpart, 16);
    vpart += __shfl_xor(vpart, 32);
    if (quad == 0) vf[grow] = vpart;

    // 8 col tiles: 0..3 -> Q (prescaled), 4..7 -> K; stage bf16 into LDS
    #pragma unroll
    for (int t = 0; t < 8; ++t) {
        const ushort* wrow = Wt + (size_t)(t * 16 + col) * 128 + quad * 8;
        f32x4 acc = {0.f, 0.f, 0.f, 0.f};
        #pragma unroll
        for (int c = 0; c < 4; ++c) {
            bf16x8 bfr = *(const bf16x8*)(wrow + c * 32);
            acc = __builtin_amdgcn_mfma_f32_16x16x32_bf16(af[c], bfr, acc, 0, 0, 0);
        }
        const int cb = (t & 3) * 16 + col;
        const int rl = wave * 16 + quad * 4;      // row within block
        #pragma unroll
        for (int r = 0; r < 4; ++r) {
            if (t < 4) qs[rl + r][cb] = f2bf(acc[r]);
            else       ks[rl + r][cb] = f2bf(acc[r]);
        }
    }
    __syncthreads();

    // coalesced write-back: thread tid -> row tid>>2, 32B chunk tid&3
    {
        const int orow = tid >> 2, och = tid & 3;
        const size_t gbase = ((size_t)(blockIdx.x * 64 + orow)) * DIM + och * 16;
        uint4 a = *(const uint4*)&qs[orow][och * 16];
        uint4 b = *(const uint4*)&qs[orow][och * 16 + 8];
        *(uint4*)&Qb[gbase]     = a;
        *(uint4*)&Qb[gbase + 8] = b;
        uint4 c = *(const uint4*)&ks[orow][och * 16];
        uint4 d = *(const uint4*)&ks[orow][och * 16 + 8];
        *(uint4*)&Kb[gbase]     = c;
        *(uint4*)&Kb[gbase + 8] = d;
    }
}

// ---------------------------------------------------------------------------
// Fused attention, single-sweep, LDS exp-cache, 2 RESIDENT BLOCKS/CU.
// Evidence: R1/R2/R3/R8 -> runtime insensitive to TLP/grid/L2-locality;
// R7 -> runtime scales with issued work per CU (but 1-resident-block kills
// it). So: halve the issued work (exp2+MFMA evaluated ONCE per score via
// f16 LDS cache) while keeping 2 blocks/CU: KCOLS=16 -> cache = 2048 q x
// 16 k x f16 = 64 KB (+skew) -> 136 KB/2 blocks < 160 KB.
// Phase A: MFMA + exp2 + colsum + cache write. Phase B: cache read + FMA +
// 16-lane reduce + one atomicAdd per row (no loads/MFMA/exp2).
// ---------------------------------------------------------------------------
__global__ __launch_bounds__(1024) void k_attn(
    const ushort* __restrict__ Qb, const ushort* __restrict__ Kb,
    const float* __restrict__ vf, const float* __restrict__ bfp,
    float* __restrict__ outp)
{
    const int b    = blockIdx.y;
    const int k0   = blockIdx.x * KCOLS;
    const int tid  = threadIdx.x;
    const int wave = tid >> 6;
    const int lane = tid & 63;
    const int quad = lane >> 4;
    const int col  = lane & 15;

    extern __shared__ char smem[];
    uint2* cache = (uint2*)smem;                 // [8 qi][CPLANE]
    const int cidx = tid + (tid >> 4);           // bank-skewed slot
    __shared__ float sl[16][KCOLS];
    __shared__ float wcol[KCOLS];

    // resident K fragments: one 16-col tile, 2 chunks
    bf16x8 kf0, kf1;
    {
        const ushort* Kbase = Kb + ((size_t)(b * SEQ + k0) + col) * DIM + quad * 8;
        kf0 = *(const bf16x8*)(Kbase);
        kf1 = *(const bf16x8*)(Kbase + 32);
    }

    const ushort* Qstart = Qb + ((size_t)(b * SEQ + wave * 128 + col)) * DIM + quad * 8;

    // ---- Phase A: colsum + f16 exp-cache ----
    float l = 0.f;
    #pragma unroll
    for (int qi = 0; qi < 8; ++qi) {
        const ushort* Qtile = Qstart + qi * 16 * DIM;
        bf16x8 a0 = *(const bf16x8*)(Qtile);
        bf16x8 a1 = *(const bf16x8*)(Qtile + 32);
        f32x4 acc = {0.f, 0.f, 0.f, 0.f};
        acc = __builtin_amdgcn_mfma_f32_16x16x32_bf16(a0, kf0, acc, 0, 0, 0);
        acc = __builtin_amdgcn_mfma_f32_16x16x32_bf16(a1, kf1, acc, 0, 0, 0);
        float e0 = fast_exp2(acc.x), e1 = fast_exp2(acc.y);
        float e2 = fast_exp2(acc.z), e3 = fast_exp2(acc.w);
        l += (e0 + e1) + (e2 + e3);
        cache[qi * CPLANE + cidx] = make_uint2(packf16(e0, e1), packf16(e2, e3));
    }
    l += __shfl_xor(l, 16);
    l += __shfl_xor(l, 32);
    if (quad == 0) sl[wave][col] = l;
    __syncthreads();
    if (tid < KCOLS) {
        float ll = 0.f;
        #pragma unroll
        for (int w = 0; w < 16; ++w) ll += sl[w][tid];
        wcol[tid] = vf[(size_t)b * SEQ + k0 + tid] / ll;
    }
    __syncthreads();

    // ---- Phase B: cache sweep -> atomic accumulate ----
    const float bias = bfp[0] * (1.0f / NKBLK);   // each k-block adds bf/128
    const float w = wcol[col];
    float* outb = outp + (size_t)b * SEQ;

    #pragma unroll
    for (int qi = 0; qi < 8; ++qi) {
        uint2 pk = cache[qi * CPLANE + cidx];
        float2 e01 = unpackf16(pk.x);
        float2 e23 = unpackf16(pk.y);
        float rs[4] = {e01.x * w, e01.y * w, e23.x * w, e23.y * w};
        #pragma unroll
        for (int r = 0; r < 4; ++r) {
            float v = rs[r];
            v += __shfl_xor(v, 1); v += __shfl_xor(v, 2);
            v += __shfl_xor(v, 4); v += __shfl_xor(v, 8);
            rs[r] = v;
        }
        if (col == 0) {
            const int qrow = wave * 128 + qi * 16 + quad * 4;
            #pragma unroll
            for (int r = 0; r < 4; ++r)
                atomicAdd(&outb[qrow + r], rs[r] + bias);
        }
    }
}

// ---------------------------------------------------------------------------
extern "C" void kernel_launch(void* const* d_in, const int* in_sizes, int n_in,
                              void* d_out, int out_size, void* d_ws, size_t ws_size,
                              hipStream_t stream) {
    (void)in_sizes; (void)n_in; (void)ws_size;
    const float* x  = (const float*)d_in[0];
    const float* Wq = (const float*)d_in[1];
    const float* Wk = (const float*)d_in[2];
    const float* Wv = (const float*)d_in[3];
    const float* Wf = (const float*)d_in[4];
    const float* bf = (const float*)d_in[5];
    float* outp = (float*)d_out;

    float*  wvf = (float*)d_ws;                                  // 256 floats
    float*  vf  = wvf + 256;                                     // B*S
    float*  pe  = vf + (size_t)BATCH * SEQ;                      // S*H f32 (1 MB)
    ushort* Wt  = (ushort*)(pe + (size_t)SEQ * HID);             // 128*128
    ushort* Qb  = Wt + 128 * 128;                                // B*S*D bf16
    ushort* Kb  = Qb + (size_t)BATCH * SEQ * DIM;                // B*S*D bf16

    static bool attr_set = false;
    if (!attr_set) {
        hipFuncSetAttribute((const void*)k_attn,
                            hipFuncAttributeMaxDynamicSharedMemorySize,
                            CACHE_BYTES);
        attr_set = true;
    }

    hipMemsetAsync(d_out, 0, (size_t)out_size * sizeof(float), stream);
    k_prep<<<SEQ * HID / 256, 256, 0, stream>>>(Wq, Wk, Wv, Wf, Wt, wvf, pe);
    k_qkv<<<BATCH * SEQ / 64, 256, 0, stream>>>(x, Wt, wvf, pe, Qb, Kb, vf);
    k_attn<<<dim3(SEQ / KCOLS, BATCH), 1024, CACHE_BYTES, stream>>>(Qb, Kb, vf, bf, outp);
}